// Round 4
// baseline (174.279 us; speedup 1.0000x reference)
//
#include <hip/hip_runtime.h>

// TripletLoss batch-hard mining, N=8192, D=256, 64 classes, margin 0.3.
// R3 (resubmit — R3 bench was a GPU-acquisition timeout, no data):
// mine_kernel with NO LDS and NO barriers. X (bf16, 4MB) fits in each XCD's
// 4MB L2, so MFMA fragments load directly from global (per-lane dwordx4,
// 100% L2-hit) — removes the 2-iteration barrier-drain structure that held
// R2 at 7.5% MfmaUtil / 17% occupancy. Triangle tiles + dual row/col mining
// kept from R2.

#define N_PTS 8192
#define DIM   256
#define MARGIN 0.3f
#define NT    64          // 8192/128 tiles per dim
#define NPAIR 2080        // NT*(NT+1)/2 upper-triangle tiles

typedef __attribute__((ext_vector_type(8))) short bf16x8;
typedef __attribute__((ext_vector_type(4))) float f32x4;

__device__ __forceinline__ unsigned short f2bf(float f) {
    unsigned u = __float_as_uint(f);
    u += 0x7FFFu + ((u >> 16) & 1u);   // round-to-nearest-even
    return (unsigned short)(u >> 16);
}

// ---------------------------------------------------------------- prep ----
// wave-per-row: lane l handles cols [4l,4l+4). bf16 copy + row sq-norm +
// init hp2 (0.0f) / hn2 (+inf).
__global__ void prep_kernel(const float* __restrict__ X,
                            unsigned short* __restrict__ Xb,
                            float* __restrict__ sq,
                            unsigned* __restrict__ hp2,
                            unsigned* __restrict__ hn2) {
    int t = blockIdx.x * 256 + threadIdx.x;     // t = row*64 + lane
    int row = t >> 6;
    int lane = t & 63;
    float4 v = reinterpret_cast<const float4*>(X)[t];
    ushort4 b4;
    b4.x = f2bf(v.x); b4.y = f2bf(v.y); b4.z = f2bf(v.z); b4.w = f2bf(v.w);
    reinterpret_cast<ushort4*>(Xb)[t] = b4;
    float p = v.x * v.x + v.y * v.y + v.z * v.z + v.w * v.w;
    #pragma unroll
    for (int m = 1; m < 64; m <<= 1) p += __shfl_xor(p, m, 64);
    if (lane == 0) {
        sq[row]  = p;
        hp2[row] = 0u;           // 0.0f : "no positive with d2>0 yet"
        hn2[row] = 0x7F800000u;  // +inf : "no negative yet"
    }
}

// ---------------------------------------------------------------- mine ----
// 128x128 tile, upper triangle only (bi<=bj). 4 waves 2x2, each wave 64x64
// via acc[4][4] of 16x16x32 bf16 MFMA. Fragments load straight from L2:
// lane l of wave (wr,wc) reads A row (R0+wr*64+m*16+(l&15)), k-bytes
// [kk*64 + (l>>4)*16, +16) — matches the MFMA A/B operand layout, so the
// load IS the fragment. No LDS, no __syncthreads. Epilogue mines rows AND
// cols (idempotent atomics make the diagonal safe).
__launch_bounds__(256, 3)
__global__ void mine_kernel(const unsigned short* __restrict__ Xb,
                            const float* __restrict__ sq,
                            const int* __restrict__ labels,
                            unsigned* __restrict__ hp2,
                            unsigned* __restrict__ hn2) {
    // XCD-aware swizzle: 2080 = 8*260, bijective contiguous chunks per XCD.
    int t = blockIdx.x;
    int swz = (t & 7) * (NPAIR / 8) + (t >> 3);
    // decode upper-triangle row-major: swz -> (bi, bj), bi <= bj
    int bi = 0, rem = swz;
    while (rem >= NT - bi) { rem -= NT - bi; ++bi; }
    int bj = bi + rem;
    int R0 = bi * 128, C0 = bj * 128;

    int tid = threadIdx.x;
    int w = tid >> 6;
    int l = tid & 63;
    int wr = w >> 1, wc = w & 1;
    int lsub = l & 15, lgrp = l >> 4;

    // per-lane fragment base pointers (bf16 elements)
    const unsigned short* pa = Xb + (size_t)(R0 + wr * 64 + lsub) * DIM + lgrp * 8;
    const unsigned short* pb = Xb + (size_t)(C0 + wc * 64 + lsub) * DIM + lgrp * 8;

    f32x4 acc[4][4];
    #pragma unroll
    for (int m = 0; m < 4; ++m)
        #pragma unroll
        for (int n = 0; n < 4; ++n) acc[m][n] = (f32x4){0.f, 0.f, 0.f, 0.f};

    #pragma unroll
    for (int kk = 0; kk < 8; ++kk) {           // K = 8 x 32
        bf16x8 a[4], b[4];
        #pragma unroll
        for (int m = 0; m < 4; ++m)
            a[m] = *reinterpret_cast<const bf16x8*>(pa + (size_t)m * 16 * DIM + kk * 32);
        #pragma unroll
        for (int n = 0; n < 4; ++n)
            b[n] = *reinterpret_cast<const bf16x8*>(pb + (size_t)n * 16 * DIM + kk * 32);
        #pragma unroll
        for (int m = 0; m < 4; ++m)
            #pragma unroll
            for (int n = 0; n < 4; ++n)
                acc[m][n] = __builtin_amdgcn_mfma_f32_16x16x32_bf16(
                    a[m], b[n], acc[m][n], 0, 0, 0);
    }

    // ---- fused mining epilogue (rows AND cols) ----
    // C/D layout: col = lane&15, row = (lane>>4)*4 + reg.
    int lc4[4]; float sc4[4];
    #pragma unroll
    for (int n = 0; n < 4; ++n) {
        int gc = C0 + wc * 64 + n * 16 + lsub;
        lc4[n] = labels[gc];
        sc4[n] = sq[gc];
    }
    const float INF = __int_as_float(0x7f800000);
    float hpc[4], hnc[4];
    #pragma unroll
    for (int n = 0; n < 4; ++n) { hpc[n] = 0.f; hnc[n] = INF; }

    #pragma unroll
    for (int m = 0; m < 4; ++m) {
        int growb = R0 + wr * 64 + m * 16 + (lgrp << 2);
        #pragma unroll
        for (int j = 0; j < 4; ++j) {
            int grow = growb + j;
            int lr = labels[grow];
            float sr = sq[grow];
            float hp = 0.f, hn = INF;
            #pragma unroll
            for (int n = 0; n < 4; ++n) {
                float d2 = fmaf(-2.f, acc[m][n][j], sr + sc4[n]);
                d2 = fmaxf(d2, 0.f);
                bool same = (lr == lc4[n]);
                hp = same ? fmaxf(hp, d2) : hp;
                hn = same ? hn : fminf(hn, d2);
                hpc[n] = same ? fmaxf(hpc[n], d2) : hpc[n];   // col anchors
                hnc[n] = same ? hnc[n] : fminf(hnc[n], d2);
            }
            #pragma unroll
            for (int s = 1; s < 16; s <<= 1) {    // reduce 16 col-lanes
                hp = fmaxf(hp, __shfl_xor(hp, s, 64));
                hn = fminf(hn, __shfl_xor(hn, s, 64));
            }
            if (lsub == 0) {
                // d2 >= 0 -> float order == signed-int bit order
                atomicMax(reinterpret_cast<int*>(hp2) + grow, __float_as_int(hp));
                atomicMin(reinterpret_cast<int*>(hn2) + grow, __float_as_int(hn));
            }
        }
    }
    // col-anchor reduce across the 4 row-groups (lanes l, l^16, l^32, l^48)
    #pragma unroll
    for (int n = 0; n < 4; ++n) {
        float p = hpc[n], q = hnc[n];
        p = fmaxf(p, __shfl_xor(p, 16, 64));
        q = fminf(q, __shfl_xor(q, 16, 64));
        p = fmaxf(p, __shfl_xor(p, 32, 64));
        q = fminf(q, __shfl_xor(q, 32, 64));
        if (l < 16) {
            int gc = C0 + wc * 64 + n * 16 + l;
            atomicMax(reinterpret_cast<int*>(hp2) + gc, __float_as_int(p));
            atomicMin(reinterpret_cast<int*>(hn2) + gc, __float_as_int(q));
        }
    }
}

// ------------------------------------------------------------ finalize ----
__global__ void finalize_kernel(const unsigned* __restrict__ hp2,
                                const unsigned* __restrict__ hn2,
                                const int* __restrict__ labels,
                                float* __restrict__ out) {
    __shared__ int hist[64];
    __shared__ float ss[4], cc[4];
    if (threadIdx.x < 64) hist[threadIdx.x] = 0;
    __syncthreads();
    for (int i = threadIdx.x; i < N_PTS; i += 256)
        atomicAdd(&hist[labels[i]], 1);
    __syncthreads();

    float s = 0.f, c = 0.f;
    for (int i = threadIdx.x; i < N_PTS; i += 256) {
        float hp = __uint_as_float(hp2[i]);
        float hn = __uint_as_float(hn2[i]);
        int h = hist[labels[i]];
        bool valid = (h > 1) && (h < N_PTS) && (hp > 0.f) && (hn < 3.0e38f);
        if (valid) {
            s += fmaxf(sqrtf(hp) - sqrtf(hn) + MARGIN, 0.f);
            c += 1.f;
        }
    }
    #pragma unroll
    for (int m = 1; m < 64; m <<= 1) {
        s += __shfl_xor(s, m, 64);
        c += __shfl_xor(c, m, 64);
    }
    int w = threadIdx.x >> 6, lv = threadIdx.x & 63;
    if (lv == 0) { ss[w] = s; cc[w] = c; }
    __syncthreads();
    if (threadIdx.x == 0) {
        float S = ss[0] + ss[1] + ss[2] + ss[3];
        float C = cc[0] + cc[1] + cc[2] + cc[3];
        out[0] = (C > 0.f) ? (S / C) : 0.f;
    }
}

// -------------------------------------------------------------- launch ----
extern "C" void kernel_launch(void* const* d_in, const int* in_sizes, int n_in,
                              void* d_out, int out_size, void* d_ws, size_t ws_size,
                              hipStream_t stream) {
    const float* X      = (const float*)d_in[0];
    const int*   labels = (const int*)d_in[1];
    float*       out    = (float*)d_out;

    char* ws = (char*)d_ws;
    unsigned short* Xb = (unsigned short*)ws;                       // 4 MB
    float*    sq  = (float*)(ws + (size_t)N_PTS * DIM * 2);
    unsigned* hp2 = (unsigned*)((char*)sq  + N_PTS * sizeof(float));
    unsigned* hn2 = (unsigned*)((char*)hp2 + N_PTS * sizeof(unsigned));

    prep_kernel<<<N_PTS / 4, 256, 0, stream>>>(X, Xb, sq, hp2, hn2);
    mine_kernel<<<NPAIR, 256, 0, stream>>>(Xb, sq, labels, hp2, hn2);
    finalize_kernel<<<1, 256, 0, stream>>>(hp2, hn2, labels, out);
}

// Round 5
// 112.886 us; speedup vs baseline: 1.5438x; 1.5438x over previous
//
#include <hip/hip_runtime.h>

// TripletLoss batch-hard mining, N=8192, D=256, 64 classes, margin 0.3.
// R5: full restructure.
//  - prep re-tiles X (bf16) into MFMA-fragment-native layout: ushort addr
//      = Rg*4096 + kk*512 + lane*8   (Rg = row/16, kk = k/32)
//    so every fragment load is a coalesced, contiguous 1KB wave-burst.
//  - mine: 256 blocks (64 row-panels x 4 col-quarters) x 512 thr (8 waves).
//    Wave keeps its 64-row A-panel (full K) in 128 VGPRs, sweeps 512 cols
//    in 16 steps of 32 cols. No LDS, no barriers, no atomics. Per-row
//    running max/min of (sc - 2*dot) folded in-register; one write per
//    (slot,row) into vp/vn[16][8192] partials (each slot single-writer).
//  - finalizeA (32 blocks): per-row reduce of 16 partials + validity +
//    per-block sums; finalizeB (1 wave): final mean.

#define N_PTS 8192
#define DIM   256
#define MARGIN 0.3f

typedef __attribute__((ext_vector_type(8))) short bf16x8;
typedef __attribute__((ext_vector_type(4))) float f32x4;

__device__ __forceinline__ unsigned short f2bf(float f) {
    unsigned u = __float_as_uint(f);
    u += 0x7FFFu + ((u >> 16) & 1u);   // round-to-nearest-even
    return (unsigned short)(u >> 16);
}

// ---------------------------------------------------------------- prep ----
// Phase A: row sq-norms (wave-per-row, coalesced float4 reads).
// Phase B: relayout X -> fragment-native bf16 tiles (coalesced ushort4
// writes; ushort4 index i within an Rg: i = kk*128 + lgrp*32 + lsub*2 + half).
__global__ void prep_kernel(const float* __restrict__ X,
                            unsigned short* __restrict__ Xb,
                            float* __restrict__ sq) {
    int t = blockIdx.x * 256 + threadIdx.x;
    {   // phase A: t = row*64 + lane, lane covers k [4l,4l+4)
        int row = t >> 6, lane = t & 63;
        float4 v = reinterpret_cast<const float4*>(X)[t];
        float p = v.x * v.x + v.y * v.y + v.z * v.z + v.w * v.w;
        #pragma unroll
        for (int m = 1; m < 64; m <<= 1) p += __shfl_xor(p, m, 64);
        if (lane == 0) sq[row] = p;
    }
    {   // phase B: t = output ushort4 index
        int i    = t & 1023;
        int Rg   = t >> 10;
        int half = i & 1;
        int lsub = (i >> 1) & 15;
        int lgrp = (i >> 5) & 3;
        int kk   = (i >> 7) & 7;
        int row  = Rg * 16 + lsub;
        int sidx = row * 64 + kk * 8 + lgrp * 2 + half;   // float4 index
        float4 v = reinterpret_cast<const float4*>(X)[sidx];
        ushort4 b4;
        b4.x = f2bf(v.x); b4.y = f2bf(v.y); b4.z = f2bf(v.z); b4.w = f2bf(v.w);
        reinterpret_cast<ushort4*>(Xb)[t] = b4;
    }
}

// ---------------------------------------------------------------- mine ----
__launch_bounds__(512, 2)
__global__ void mine_kernel(const unsigned short* __restrict__ Xb,
                            const float* __restrict__ sq,
                            const int* __restrict__ labels,
                            float* __restrict__ vp,
                            float* __restrict__ vn) {
    int bid = blockIdx.x;
    int panel = bid >> 2;            // 64 row-panels of 128
    int q     = bid & 3;             // 4 col-quarters of 2048
    int tid = threadIdx.x;
    int w = tid >> 6, l = tid & 63;
    int wr = w >> 2, wc = w & 3;     // wave: rows wr*64, cols wc*512
    int lsub = l & 15, lgrp = l >> 4;

    const float INF = __int_as_float(0x7f800000);

    // A-panel: 64 rows x K=256 in registers. Rg(m) = panel*8 + wr*4 + m.
    const unsigned short* abase = Xb + (size_t)(panel * 8 + wr * 4) * 4096 + l * 8;
    bf16x8 a[4][8];
    #pragma unroll
    for (int m = 0; m < 4; ++m)
        #pragma unroll
        for (int kk = 0; kk < 8; ++kk)
            a[m][kk] = *reinterpret_cast<const bf16x8*>(abase + m * 4096 + kk * 512);

    // anchor labels for this lane's 16 (m,j) rows
    int rowbase = panel * 128 + wr * 64;
    int lrj[4][4];
    #pragma unroll
    for (int m = 0; m < 4; ++m)
        #pragma unroll
        for (int j = 0; j < 4; ++j)
            lrj[m][j] = labels[rowbase + m * 16 + lgrp * 4 + j];

    float vpr[4][4], vnr[4][4];      // running max/min of (sc - 2*dot)
    #pragma unroll
    for (int m = 0; m < 4; ++m)
        #pragma unroll
        for (int j = 0; j < 4; ++j) { vpr[m][j] = -INF; vnr[m][j] = INF; }

    int colwave = q * 2048 + wc * 512;
    const unsigned short* bbase = Xb + (size_t)(colwave >> 4) * 4096 + l * 8;

    for (int cs = 0; cs < 16; ++cs) {          // 16 col-steps of 32
        int colbase = colwave + cs * 32;
        int lc0 = labels[colbase + lsub];
        int lc1 = labels[colbase + 16 + lsub];
        float sc0 = sq[colbase + lsub];
        float sc1 = sq[colbase + 16 + lsub];

        f32x4 acc[4][2];
        #pragma unroll
        for (int m = 0; m < 4; ++m) {
            acc[m][0] = (f32x4){0.f, 0.f, 0.f, 0.f};
            acc[m][1] = (f32x4){0.f, 0.f, 0.f, 0.f};
        }

        const unsigned short* bb = bbase + (size_t)cs * 8192;
        #pragma unroll
        for (int kp = 0; kp < 4; ++kp) {       // 2 kk per kp
            bf16x8 b00 = *reinterpret_cast<const bf16x8*>(bb + kp * 1024);
            bf16x8 b01 = *reinterpret_cast<const bf16x8*>(bb + 4096 + kp * 1024);
            bf16x8 b10 = *reinterpret_cast<const bf16x8*>(bb + kp * 1024 + 512);
            bf16x8 b11 = *reinterpret_cast<const bf16x8*>(bb + 4096 + kp * 1024 + 512);
            #pragma unroll
            for (int m = 0; m < 4; ++m) {
                acc[m][0] = __builtin_amdgcn_mfma_f32_16x16x32_bf16(
                    a[m][2 * kp], b00, acc[m][0], 0, 0, 0);
                acc[m][1] = __builtin_amdgcn_mfma_f32_16x16x32_bf16(
                    a[m][2 * kp], b01, acc[m][1], 0, 0, 0);
            }
            #pragma unroll
            for (int m = 0; m < 4; ++m) {
                acc[m][0] = __builtin_amdgcn_mfma_f32_16x16x32_bf16(
                    a[m][2 * kp + 1], b10, acc[m][0], 0, 0, 0);
                acc[m][1] = __builtin_amdgcn_mfma_f32_16x16x32_bf16(
                    a[m][2 * kp + 1], b11, acc[m][1], 0, 0, 0);
            }
        }

        // fold: val = sc - 2*dot; track max over same-label, min over diff.
        #pragma unroll
        for (int m = 0; m < 4; ++m)
            #pragma unroll
            for (int j = 0; j < 4; ++j) {
                int lr = lrj[m][j];
                float v0 = fmaf(-2.f, acc[m][0][j], sc0);
                float v1 = fmaf(-2.f, acc[m][1][j], sc1);
                bool s0 = (lr == lc0), s1 = (lr == lc1);
                vpr[m][j] = fmaxf(vpr[m][j], s0 ? v0 : -INF);
                vpr[m][j] = fmaxf(vpr[m][j], s1 ? v1 : -INF);
                vnr[m][j] = fminf(vnr[m][j], s0 ? INF : v0);
                vnr[m][j] = fminf(vnr[m][j], s1 ? INF : v1);
            }
    }

    // reduce over the 16 lsub lanes; write single-writer partial slot.
    int slot = q * 4 + wc;
    #pragma unroll
    for (int m = 0; m < 4; ++m)
        #pragma unroll
        for (int j = 0; j < 4; ++j) {
            float p = vpr[m][j], n = vnr[m][j];
            #pragma unroll
            for (int s = 1; s < 16; s <<= 1) {
                p = fmaxf(p, __shfl_xor(p, s, 64));
                n = fminf(n, __shfl_xor(n, s, 64));
            }
            if (lsub == 0) {
                int row = rowbase + m * 16 + lgrp * 4 + j;
                vp[slot * N_PTS + row] = p;
                vn[slot * N_PTS + row] = n;
            }
        }
}

// ------------------------------------------------------------ finalizeA ----
// 32 blocks x 256: one thread per anchor row; reduce 16 partial slots,
// apply validity, emit per-block sum/count.
__global__ void finalizeA_kernel(const float* __restrict__ vp,
                                 const float* __restrict__ vn,
                                 const float* __restrict__ sq,
                                 const int* __restrict__ labels,
                                 float* __restrict__ bsum,
                                 float* __restrict__ bcnt) {
    __shared__ int hist[64];
    __shared__ float ss[4], cc[4];
    int tid = threadIdx.x;
    if (tid < 64) hist[tid] = 0;
    __syncthreads();
    for (int i = tid; i < N_PTS; i += 256) atomicAdd(&hist[labels[i]], 1);
    __syncthreads();

    const float INF = __int_as_float(0x7f800000);
    int r = blockIdx.x * 256 + tid;
    float mp = -INF, mn = INF;
    #pragma unroll
    for (int s = 0; s < 16; ++s) {
        mp = fmaxf(mp, vp[s * N_PTS + r]);
        mn = fminf(mn, vn[s * N_PTS + r]);
    }
    float sr = sq[r];
    float hp2 = sr + mp;                    // hardest-pos d^2 (unclamped)
    float hn2 = fmaxf(sr + mn, 0.f);        // hardest-neg d^2, clamped
    int h = hist[labels[r]];
    bool valid = (h > 1) && (h < N_PTS) && (hp2 > 0.f);
    float contrib = valid ? fmaxf(sqrtf(hp2) - sqrtf(hn2) + MARGIN, 0.f) : 0.f;
    float cnt = valid ? 1.f : 0.f;

    #pragma unroll
    for (int m = 1; m < 64; m <<= 1) {
        contrib += __shfl_xor(contrib, m, 64);
        cnt     += __shfl_xor(cnt, m, 64);
    }
    int wv = tid >> 6, lv = tid & 63;
    if (lv == 0) { ss[wv] = contrib; cc[wv] = cnt; }
    __syncthreads();
    if (tid == 0) {
        bsum[blockIdx.x] = ss[0] + ss[1] + ss[2] + ss[3];
        bcnt[blockIdx.x] = cc[0] + cc[1] + cc[2] + cc[3];
    }
}

// ------------------------------------------------------------ finalizeB ----
__global__ void finalizeB_kernel(const float* __restrict__ bsum,
                                 const float* __restrict__ bcnt,
                                 float* __restrict__ out) {
    int l = threadIdx.x;
    float s = (l < 32) ? bsum[l] : 0.f;
    float c = (l < 32) ? bcnt[l] : 0.f;
    #pragma unroll
    for (int m = 1; m < 64; m <<= 1) {
        s += __shfl_xor(s, m, 64);
        c += __shfl_xor(c, m, 64);
    }
    if (l == 0) out[0] = (c > 0.f) ? (s / c) : 0.f;
}

// -------------------------------------------------------------- launch ----
extern "C" void kernel_launch(void* const* d_in, const int* in_sizes, int n_in,
                              void* d_out, int out_size, void* d_ws, size_t ws_size,
                              hipStream_t stream) {
    const float* X      = (const float*)d_in[0];
    const int*   labels = (const int*)d_in[1];
    float*       out    = (float*)d_out;

    char* ws = (char*)d_ws;
    unsigned short* Xb = (unsigned short*)ws;                    // 4 MB
    float* sq   = (float*)(ws + 4194304);                        // 32 KB
    float* vp   = (float*)(ws + 4194304 + 32768);                // 512 KB
    float* vn   = (float*)(ws + 4194304 + 32768 + 524288);       // 512 KB
    float* bsum = (float*)(ws + 4194304 + 32768 + 1048576);      // 128 B
    float* bcnt = (float*)(ws + 4194304 + 32768 + 1048576 + 128);

    prep_kernel<<<2048, 256, 0, stream>>>(X, Xb, sq);
    mine_kernel<<<256, 512, 0, stream>>>(Xb, sq, labels, vp, vn);
    finalizeA_kernel<<<32, 256, 0, stream>>>(vp, vn, sq, labels, bsum, bcnt);
    finalizeB_kernel<<<1, 64, 0, stream>>>(bsum, bcnt, out);
}